// Round 1
// baseline (605.757 us; speedup 1.0000x reference)
//
#include <hip/hip_runtime.h>
#include <stdint.h>

#pragma clang fp contract(off)

#define B_    16
#define C_    128
#define HW_   56
#define L_    3136      // 56*56
#define CO_   128
#define F_    1152      // 128*9
#define M_    50176     // 16*3136

// ---- workspace layout (bytes) ----
#define OFF_SW   256        // float scale_w[128]
#define OFF_ZPW  768        // int   zp_w[128]
#define OFF_CT   1280       // int   const_term[128] = zp_x*qw_sum + K*zp_w*zp_x + qb
#define OFF_QW   4096       // int8  qw_packed[c][o][12]  (9 taps + 3 zero pad) = 196608
#define OFF_QX   204800     // int8  qx[b][c][56][56] = 6422528
#define OFF_S    6627328    // int   S[b][3136] channel-sums = 200704
#define OFF_SQ   6828032    // int   sum_qx[50176] = 200704
#define OFF_RES  7028736    // int   res[50176][128] = 25690112  (end ~31.2 MB)

struct QP { unsigned xmin_enc, xmax_enc; int rmin, rmax; };

__device__ __forceinline__ unsigned enc_f(float f) {
    unsigned u = __float_as_uint(f);
    return (u & 0x80000000u) ? ~u : (u | 0x80000000u);
}
__device__ __forceinline__ float dec_f(unsigned e) {
    return __uint_as_float((e & 0x80000000u) ? (e ^ 0x80000000u) : ~e);
}
__device__ __forceinline__ int read_abit(const int* p) {
    int i = *p;
    if (i > 0 && i < 32) return i;
    float f = __int_as_float(i);
    int fi = (int)f;
    return (fi > 0 && fi < 32) ? fi : 8;
}
// scale_x / zp_x exactly as asym_quant_params (f32, round-half-even)
__device__ __forceinline__ void get_sx(const QP* P, int abit, float& sx, float& zx) {
    float xmin = dec_f(P->xmin_enc), xmax = dec_f(P->xmax_enc);
    float n = (float)((1 << abit) - 1);
    sx = n / fmaxf(xmax - xmin, 1e-8f);
    zx = rintf(sx * xmin) + (float)(1 << (abit - 1));
}

// ---------------- kernels ----------------

__global__ void k_init(char* ws) {
    if (threadIdx.x == 0) {
        QP* P = (QP*)ws;
        P->xmin_enc = 0x80000000u;  // enc(0.0f): padding zeros included in min/max
        P->xmax_enc = 0x80000000u;
        P->rmin = INT32_MAX;
        P->rmax = INT32_MIN;
    }
}

__global__ void k_xminmax(const float4* __restrict__ x4, int n4, char* ws) {
    QP* P = (QP*)ws;
    float mn = 0.0f, mx = 0.0f;
    int stride = gridDim.x * blockDim.x;
    for (int i = blockIdx.x * blockDim.x + threadIdx.x; i < n4; i += stride) {
        float4 v = x4[i];
        mn = fminf(mn, fminf(fminf(v.x, v.y), fminf(v.z, v.w)));
        mx = fmaxf(mx, fmaxf(fmaxf(v.x, v.y), fmaxf(v.z, v.w)));
    }
    for (int m = 32; m; m >>= 1) {
        mn = fminf(mn, __shfl_xor(mn, m));
        mx = fmaxf(mx, __shfl_xor(mx, m));
    }
    __shared__ float smn[4], smx[4];
    int w = threadIdx.x >> 6;
    if ((threadIdx.x & 63) == 0) { smn[w] = mn; smx[w] = mx; }
    __syncthreads();
    if (threadIdx.x == 0) {
        mn = fminf(fminf(smn[0], smn[1]), fminf(smn[2], smn[3]));
        mx = fmaxf(fmaxf(smx[0], smx[1]), fmaxf(smx[2], smx[3]));
        atomicMin(&P->xmin_enc, enc_f(mn));   // float order == enc order
        atomicMax(&P->xmax_enc, enc_f(mx));
    }
}

// one wave per output channel
__global__ void k_wquant(const float* __restrict__ w, const float* __restrict__ bias,
                         const int* __restrict__ abit_p, char* ws) {
    QP* P = (QP*)ws;
    float* scale_w = (float*)(ws + OFF_SW);
    int* zpw = (int*)(ws + OFF_ZPW);
    int* ct  = (int*)(ws + OFF_CT);
    signed char* qw = (signed char*)(ws + OFF_QW);

    int o = blockIdx.x, lane = threadIdx.x;
    const float* wr = w + o * F_;
    float mn = 3.4e38f, mx = -3.4e38f;
    for (int f = lane; f < F_; f += 64) {
        float v = wr[f];
        mn = fminf(mn, v); mx = fmaxf(mx, v);
    }
    for (int m = 32; m; m >>= 1) {
        mn = fminf(mn, __shfl_xor(mn, m));
        mx = fmaxf(mx, __shfl_xor(mx, m));
    }
    float sw = 255.0f / fmaxf(mx - mn, 1e-8f);       // WEIGHT_BIT = 8
    float zw = rintf(sw * mn) + 128.0f;

    int qsum = 0;
    for (int f = lane; f < F_; f += 64) {
        float q = fminf(fmaxf(rintf(sw * wr[f] - zw), -128.0f), 127.0f);
        int qi = (int)q;
        qsum += qi;
        int c = f / 9, j = f - c * 9;
        qw[(c * CO_ + o) * 12 + j] = (signed char)qi;
    }
    for (int c = lane; c < C_; c += 64) {            // zero the 3 pad taps
        qw[(c * CO_ + o) * 12 + 9]  = 0;
        qw[(c * CO_ + o) * 12 + 10] = 0;
        qw[(c * CO_ + o) * 12 + 11] = 0;
    }
    for (int m = 32; m; m >>= 1) qsum += __shfl_xor(qsum, m);
    if (lane == 0) {
        int abit = read_abit(abit_p);
        float sx, zx; get_sx(P, abit, sx, zx);
        float qb = rintf(sw * sx * bias[o]);         // ((sw*sx)*bias), then round
        int zwi = (int)zw, zxi = (int)zx;
        ct[o] = zxi * qsum + F_ * zwi * zxi + (int)qb;
        zpw[o] = zwi;
        scale_w[o] = sw;
    }
}

__global__ void k_xquant(const float4* __restrict__ x4, int n4,
                         const int* __restrict__ abit_p, char* ws) {
    QP* P = (QP*)ws;
    int abit = read_abit(abit_p);
    float sx, zx; get_sx(P, abit, sx, zx);
    int nx = 1 << (abit - 1);
    float lo = -(float)nx, hi = (float)(nx - 1);
    int* qx = (int*)(ws + OFF_QX);
    int stride = gridDim.x * blockDim.x;
    for (int i = blockIdx.x * blockDim.x + threadIdx.x; i < n4; i += stride) {
        float4 v = x4[i];
        int a = (int)fminf(fmaxf(rintf(sx * v.x - zx), lo), hi);
        int b = (int)fminf(fmaxf(rintf(sx * v.y - zx), lo), hi);
        int c = (int)fminf(fmaxf(rintf(sx * v.z - zx), lo), hi);
        int d = (int)fminf(fmaxf(rintf(sx * v.w - zx), lo), hi);
        qx[i] = (a & 255) | ((b & 255) << 8) | ((c & 255) << 16) | (d << 24);
    }
}

// S[b][sp] = sum over c of qx[b][c][sp]
__global__ void k_csum(char* ws) {
    const signed char* qx = (const signed char*)(ws + OFF_QX);
    int* S = (int*)(ws + OFF_S);
    int tid = blockIdx.x * blockDim.x + threadIdx.x;   // 50176 exact
    int b = tid / L_, sp = tid - b * L_;
    const signed char* p = qx + b * C_ * L_ + sp;
    int s = 0;
    for (int c = 0; c < C_; ++c) s += p[c * L_];
    S[tid] = s;
}

// sum_qx[m] = 3x3 box over S with 128*q0 padding
__global__ void k_boxsum(const int* __restrict__ abit_p, char* ws) {
    QP* P = (QP*)ws;
    const int* S = (const int*)(ws + OFF_S);
    int* sq = (int*)(ws + OFF_SQ);
    int abit = read_abit(abit_p);
    float sx, zx; get_sx(P, abit, sx, zx);
    int nx = 1 << (abit - 1);
    int q0 = min(max(-(int)zx, -nx), nx - 1);
    int pad = C_ * q0;
    int m = blockIdx.x * blockDim.x + threadIdx.x;     // 50176 exact
    int b = m / L_, l = m - b * L_;
    int oh = l / HW_, ow = l - oh * HW_;
    const int* Sb = S + b * L_;
    int s = 0;
    for (int kh = 0; kh < 3; ++kh) {
        int ih = oh - 1 + kh;
        for (int kw = 0; kw < 3; ++kw) {
            int iw = ow - 1 + kw;
            s += (ih >= 0 && ih < HW_ && iw >= 0 && iw < HW_) ? Sb[ih * HW_ + iw] : pad;
        }
    }
    sq[m] = s;
}

// 64M x 128N int8 GEMM tile per block, implicit im2col, K-loop over channels
__global__ __launch_bounds__(256) void k_gemm(const int* __restrict__ abit_p, char* ws) {
    __shared__ int a_s[64 * 3];    // 64 rows x 12 int8 (3 words)
    __shared__ int b_s[128 * 3];   // 128 cols x 12 int8
    __shared__ int red[8];

    QP* P = (QP*)ws;
    const signed char* qx = (const signed char*)(ws + OFF_QX);
    const int* qw_w  = (const int*)(ws + OFF_QW);
    const int* sumqx = (const int*)(ws + OFF_SQ);
    const int* zpw   = (const int*)(ws + OFF_ZPW);
    const int* ct    = (const int*)(ws + OFF_CT);
    int* res = (int*)(ws + OFF_RES);

    int t = threadIdx.x;
    int mg = blockIdx.x * 64;          // 3136 % 64 == 0: tiles never cross batch
    int b = mg / L_, l0 = mg - b * L_;

    int abit = read_abit(abit_p);
    float sx, zx; get_sx(P, abit, sx, zx);
    int nx = 1 << (abit - 1);
    int q0 = min(max(-(int)zx, -nx), nx - 1);

    // staging-A precompute: thread t<192 owns (row sm, word sseg)
    int sm = t / 3, sseg = t - sm * 3;
    int offs[4];
    if (t < 192) {
        int sl = l0 + sm;
        int soh = sl / HW_, sow = sl - soh * HW_;
        #pragma unroll
        for (int jj = 0; jj < 4; ++jj) {
            int k = sseg * 4 + jj;
            if (k < 9) {
                int kh = k / 3, kw = k - kh * 3;
                int ih = soh - 1 + kh, iw = sow - 1 + kw;
                offs[jj] = (ih >= 0 && ih < HW_ && iw >= 0 && iw < HW_) ? (ih * HW_ + iw) : -1;
            } else offs[jj] = -2;      // zero pad tap (qw pad is 0 anyway)
        }
    }

    int tm = t & 7, to = t >> 3;       // 8 m-rows x 4 o-cols per thread
    int acc[8][4];
    #pragma unroll
    for (int i = 0; i < 8; ++i)
        #pragma unroll
        for (int j = 0; j < 4; ++j) acc[i][j] = 0;

    const signed char* qxb = qx + b * C_ * L_;
    for (int c = 0; c < C_; ++c) {
        if (t < 192) {
            const signed char* qc = qxb + c * L_;
            int wv = 0;
            #pragma unroll
            for (int jj = 0; jj < 4; ++jj) {
                int v = (offs[jj] >= 0) ? (int)qc[offs[jj]] : ((offs[jj] == -1) ? q0 : 0);
                wv |= (v & 255) << (8 * jj);
            }
            a_s[sm * 3 + sseg] = wv;
        }
        {
            int base = c * 384;                     // [c][o][12] words
            for (int wdx = t; wdx < 384; wdx += 256) b_s[wdx] = qw_w[base + wdx];
        }
        __syncthreads();
        #pragma unroll
        for (int seg = 0; seg < 3; ++seg) {
            int bu[4][4];
            #pragma unroll
            for (int j = 0; j < 4; ++j) {
                int bw = b_s[(to * 4 + j) * 3 + seg];
                bu[j][0] = (bw << 24) >> 24;
                bu[j][1] = (bw << 16) >> 24;
                bu[j][2] = (bw << 8) >> 24;
                bu[j][3] = bw >> 24;
            }
            #pragma unroll
            for (int i = 0; i < 8; ++i) {
                int aw = a_s[(tm * 8 + i) * 3 + seg];
                int a0 = (aw << 24) >> 24, a1 = (aw << 16) >> 24;
                int a2 = (aw << 8) >> 24,  a3 = aw >> 24;
                #pragma unroll
                for (int j = 0; j < 4; ++j)
                    acc[i][j] += a0 * bu[j][0] + a1 * bu[j][1] + a2 * bu[j][2] + a3 * bu[j][3];
            }
        }
        __syncthreads();
    }

    // epilogue: add zero-point corrections, write res, track global min/max
    int zw4[4], ct4[4];
    #pragma unroll
    for (int j = 0; j < 4; ++j) { zw4[j] = zpw[to * 4 + j]; ct4[j] = ct[to * 4 + j]; }
    int lmin = INT32_MAX, lmax = INT32_MIN;
    #pragma unroll
    for (int i = 0; i < 8; ++i) {
        int m = mg + tm * 8 + i;
        int s = sumqx[m];
        int4 r4;
        int r0 = acc[i][0] + zw4[0] * s + ct4[0];
        int r1 = acc[i][1] + zw4[1] * s + ct4[1];
        int r2 = acc[i][2] + zw4[2] * s + ct4[2];
        int r3 = acc[i][3] + zw4[3] * s + ct4[3];
        lmin = min(lmin, min(min(r0, r1), min(r2, r3)));
        lmax = max(lmax, max(max(r0, r1), max(r2, r3)));
        r4.x = r0; r4.y = r1; r4.z = r2; r4.w = r3;
        *(int4*)(res + m * CO_ + to * 4) = r4;
    }
    for (int m = 32; m; m >>= 1) {
        lmin = min(lmin, __shfl_xor(lmin, m));
        lmax = max(lmax, __shfl_xor(lmax, m));
    }
    if ((t & 63) == 0) { red[t >> 6] = lmin; red[4 + (t >> 6)] = lmax; }
    __syncthreads();
    if (t == 0) {
        lmin = min(min(red[0], red[1]), min(red[2], red[3]));
        lmax = max(max(red[4], red[5]), max(red[6], red[7]));
        atomicMin(&P->rmin, lmin);
        atomicMax(&P->rmax, lmax);
    }
}

// requantize + dequantize, write [B][Cout][L]
__global__ void k_deq(const int* __restrict__ abit_p, char* ws, float* __restrict__ out, int n) {
    QP* P = (QP*)ws;
    const int* res = (const int*)(ws + OFF_RES);
    const float* scale_w = (const float*)(ws + OFF_SW);
    int idx = blockIdx.x * blockDim.x + threadIdx.x;
    if (idx >= n) return;
    int abit = read_abit(abit_p);
    float sx, zx; get_sx(P, abit, sx, zx);
    int nx = 1 << (abit - 1);
    float nlev = (float)((1 << abit) - 1);
    float rmin = (float)P->rmin, rmax = (float)P->rmax;
    float sr = nlev / fmaxf(rmax - rmin, 1e-8f);
    float zr = rintf(sr * rmin) + (float)nx;

    int bo = idx / L_;                 // b*128 + o
    int l = idx - bo * L_;
    int b = bo / CO_, o = bo - b * CO_;
    int r = res[(b * L_ + l) * CO_ + o];
    float q = fminf(fmaxf(rintf(sr * (float)r - zr), -(float)nx), (float)(nx - 1));
    out[idx] = ((q + zr) / sr) / (scale_w[o] * sx);
}

// ---------------- launch ----------------

extern "C" void kernel_launch(void* const* d_in, const int* in_sizes, int n_in,
                              void* d_out, int out_size, void* d_ws, size_t ws_size,
                              hipStream_t stream) {
    const float* x      = (const float*)d_in[0];
    const float* weight = (const float*)d_in[1];
    const float* bias   = (const float*)d_in[2];
    const int*   abit   = (const int*)d_in[3];
    float* out = (float*)d_out;
    char* ws = (char*)d_ws;

    int n4 = (B_ * C_ * L_) / 4;       // 1,605,632 float4s

    k_init<<<1, 64, 0, stream>>>(ws);
    k_xminmax<<<1024, 256, 0, stream>>>((const float4*)x, n4, ws);
    k_wquant<<<128, 64, 0, stream>>>(weight, bias, abit, ws);
    k_xquant<<<1024, 256, 0, stream>>>((const float4*)x, n4, abit, ws);
    k_csum<<<M_ / 256, 256, 0, stream>>>(ws);
    k_boxsum<<<M_ / 256, 256, 0, stream>>>(abit, ws);
    k_gemm<<<M_ / 64, 256, 0, stream>>>(abit, ws);
    k_deq<<<(out_size + 255) / 256, 256, 0, stream>>>(abit, ws, out, out_size);
}

// Round 2
// 104.197 us; speedup vs baseline: 5.8136x; 5.8136x over previous
//
#include <hip/hip_runtime.h>
#include <stdint.h>

#pragma clang fp contract(off)

typedef __attribute__((ext_vector_type(4))) int i32x4;
typedef __attribute__((ext_vector_type(16))) int i32x16;

#define B_    16
#define C_    128
#define HW_   56
#define L_    3136      // 56*56
#define CO_   128
#define F_    1152      // 128*9
#define M_    50176     // 16*3136

// ---- workspace layout (bytes) ----
#define OFF_SW   256        // float scale_w[128]
#define OFF_ZPW  768        // int   zp_w[128]
#define OFF_CT   1280       // int   const_term[128]
#define OFF_QW   4096       // int8  qw[j][o][c] = 9*128*128 = 147456
#define OFF_QX   153600     // int8  qx_t[b][l][c] = 6422528 (channel-last!)
#define OFF_S    6576128    // int   S[b][3136] channel-sums = 200704
#define OFF_SQ   6776832    // int   sum_qx[50176] = 200704
#define OFF_RES  6977536    // int   res[50176][128] = 25690112 (end ~32.7MB)

struct QP { unsigned xmin_enc, xmax_enc; int rmin, rmax; };

__device__ __forceinline__ unsigned enc_f(float f) {
    unsigned u = __float_as_uint(f);
    return (u & 0x80000000u) ? ~u : (u | 0x80000000u);
}
__device__ __forceinline__ float dec_f(unsigned e) {
    return __uint_as_float((e & 0x80000000u) ? (e ^ 0x80000000u) : ~e);
}
__device__ __forceinline__ int read_abit(const int* p) {
    int i = *p;
    if (i > 0 && i < 32) return i;
    float f = __int_as_float(i);
    int fi = (int)f;
    return (fi > 0 && fi < 32) ? fi : 8;
}
__device__ __forceinline__ void get_sx(const QP* P, int abit, float& sx, float& zx) {
    float xmin = dec_f(P->xmin_enc), xmax = dec_f(P->xmax_enc);
    float n = (float)((1 << abit) - 1);
    sx = n / fmaxf(xmax - xmin, 1e-8f);
    zx = rintf(sx * xmin) + (float)(1 << (abit - 1));
}

// ---------------- kernels ----------------

__global__ void k_init(char* ws) {
    if (threadIdx.x == 0) {
        QP* P = (QP*)ws;
        P->xmin_enc = 0x80000000u;  // enc(0.0f): padding zeros count
        P->xmax_enc = 0x80000000u;
        P->rmin = INT32_MAX;
        P->rmax = INT32_MIN;
    }
}

__global__ void k_xminmax(const float4* __restrict__ x4, int n4, char* ws) {
    QP* P = (QP*)ws;
    float mn = 0.0f, mx = 0.0f;
    int stride = gridDim.x * blockDim.x;
    for (int i = blockIdx.x * blockDim.x + threadIdx.x; i < n4; i += stride) {
        float4 v = x4[i];
        mn = fminf(mn, fminf(fminf(v.x, v.y), fminf(v.z, v.w)));
        mx = fmaxf(mx, fmaxf(fmaxf(v.x, v.y), fmaxf(v.z, v.w)));
    }
    for (int m = 32; m; m >>= 1) {
        mn = fminf(mn, __shfl_xor(mn, m));
        mx = fmaxf(mx, __shfl_xor(mx, m));
    }
    __shared__ float smn[4], smx[4];
    int w = threadIdx.x >> 6;
    if ((threadIdx.x & 63) == 0) { smn[w] = mn; smx[w] = mx; }
    __syncthreads();
    if (threadIdx.x == 0) {
        mn = fminf(fminf(smn[0], smn[1]), fminf(smn[2], smn[3]));
        mx = fmaxf(fmaxf(smx[0], smx[1]), fmaxf(smx[2], smx[3]));
        atomicMin(&P->xmin_enc, enc_f(mn));
        atomicMax(&P->xmax_enc, enc_f(mx));
    }
}

// one wave per output channel; packs qw as [j][o][c]
__global__ void k_wquant(const float* __restrict__ w, const float* __restrict__ bias,
                         const int* __restrict__ abit_p, char* ws) {
    QP* P = (QP*)ws;
    float* scale_w = (float*)(ws + OFF_SW);
    int* zpw = (int*)(ws + OFF_ZPW);
    int* ct  = (int*)(ws + OFF_CT);
    signed char* qw = (signed char*)(ws + OFF_QW);

    int o = blockIdx.x, lane = threadIdx.x;
    const float* wr = w + o * F_;
    float mn = 3.4e38f, mx = -3.4e38f;
    for (int f = lane; f < F_; f += 64) {
        float v = wr[f];
        mn = fminf(mn, v); mx = fmaxf(mx, v);
    }
    for (int m = 32; m; m >>= 1) {
        mn = fminf(mn, __shfl_xor(mn, m));
        mx = fmaxf(mx, __shfl_xor(mx, m));
    }
    float sw = 255.0f / fmaxf(mx - mn, 1e-8f);
    float zw = rintf(sw * mn) + 128.0f;

    int qsum = 0;
    for (int f = lane; f < F_; f += 64) {
        float q = fminf(fmaxf(rintf(sw * wr[f] - zw), -128.0f), 127.0f);
        int qi = (int)q;
        qsum += qi;
        int c = f / 9, j = f - c * 9;
        qw[(j * CO_ + o) * C_ + c] = (signed char)qi;
    }
    for (int m = 32; m; m >>= 1) qsum += __shfl_xor(qsum, m);
    if (lane == 0) {
        int abit = read_abit(abit_p);
        float sx, zx; get_sx(P, abit, sx, zx);
        float qb = rintf(sw * sx * bias[o]);
        int zwi = (int)zw, zxi = (int)zx;
        ct[o] = zxi * qsum + F_ * zwi * zxi + (int)qb;
        zpw[o] = zwi;
        scale_w[o] = sw;
    }
}

// quantize to channel-last qx_t[b][l][c] + per-pixel channel sums S[b][l]
__global__ __launch_bounds__(256) void k_xquant(const float* __restrict__ x,
                                                const int* __restrict__ abit_p, char* ws) {
    __shared__ int ssum[4][64];
    QP* P = (QP*)ws;
    int abit = read_abit(abit_p);
    float sx, zx; get_sx(P, abit, sx, zx);
    int nx = 1 << (abit - 1);
    float lo = -(float)nx, hif = (float)(nx - 1);
    signed char* qxt = (signed char*)(ws + OFF_QX);
    int gid = blockIdx.x;
    int b = gid / 49, lcq = gid - b * 49;
    int l0 = lcq * 64;
    int t = threadIdx.x;
    int lane = t & 63, cg = t >> 6;
    int l = l0 + lane;
    const float* xb = x + ((size_t)b * C_) * L_ + l;
    int4* dst = (int4*)(qxt + ((size_t)(b * L_ + l)) * 128);
    int psum = 0;
    #pragma unroll
    for (int ii = 0; ii < 2; ++ii) {
        int c16 = (cg + 4 * ii) * 16;
        int wds[4];
        #pragma unroll
        for (int k = 0; k < 4; ++k) {
            int wv = 0;
            #pragma unroll
            for (int e = 0; e < 4; ++e) {
                int c = c16 + 4 * k + e;
                float v = xb[(size_t)c * L_];
                int qi = (int)fminf(fmaxf(rintf(sx * v - zx), lo), hif);
                psum += qi;
                wv |= (qi & 255) << (8 * e);
            }
            wds[k] = wv;
        }
        int4 vv; vv.x = wds[0]; vv.y = wds[1]; vv.z = wds[2]; vv.w = wds[3];
        dst[c16 >> 4] = vv;
    }
    ssum[cg][lane] = psum;
    __syncthreads();
    if (cg == 0) {
        int* S = (int*)(ws + OFF_S);
        S[b * L_ + l] = ssum[0][lane] + ssum[1][lane] + ssum[2][lane] + ssum[3][lane];
    }
}

// sum_qx[m] = 3x3 box over S with 128*q0 padding
__global__ void k_boxsum(const int* __restrict__ abit_p, char* ws) {
    QP* P = (QP*)ws;
    const int* S = (const int*)(ws + OFF_S);
    int* sq = (int*)(ws + OFF_SQ);
    int abit = read_abit(abit_p);
    float sx, zx; get_sx(P, abit, sx, zx);
    int nx = 1 << (abit - 1);
    int q0 = min(max(-(int)zx, -nx), nx - 1);
    int pad = C_ * q0;
    int m = blockIdx.x * blockDim.x + threadIdx.x;
    int b = m / L_, l = m - b * L_;
    int oh = l / HW_, ow = l - oh * HW_;
    const int* Sb = S + b * L_;
    int s = 0;
    for (int kh = 0; kh < 3; ++kh) {
        int ih = oh - 1 + kh;
        for (int kw = 0; kw < 3; ++kw) {
            int iw = ow - 1 + kw;
            s += (ih >= 0 && ih < HW_ && iw >= 0 && iw < HW_) ? Sb[ih * HW_ + iw] : pad;
        }
    }
    sq[m] = s;
}

// 64M x 128N MFMA int8 GEMM, tap-major K (9 taps x 128 channels), implicit im2col
__global__ __launch_bounds__(256) void k_gemm(const int* __restrict__ abit_p, char* __restrict__ ws) {
    __shared__ __align__(16) signed char As[64 * 128];
    __shared__ __align__(16) signed char Bs[128 * 128];
    __shared__ int red[8];

    QP* P = (QP*)ws;
    const signed char* qxt = (const signed char*)(ws + OFF_QX);
    const signed char* qw  = (const signed char*)(ws + OFF_QW);
    const int* sumqx = (const int*)(ws + OFF_SQ);
    const int* zpw   = (const int*)(ws + OFF_ZPW);
    const int* ct    = (const int*)(ws + OFF_CT);
    int* res = (int*)(ws + OFF_RES);

    int t = threadIdx.x;
    int mg = blockIdx.x * 64;
    int b = mg / L_, l0 = mg - b * L_;

    int abit = read_abit(abit_p);
    float sx, zx; get_sx(P, abit, sx, zx);
    int nx = 1 << (abit - 1);
    int q0 = min(max(-(int)zx, -nx), nx - 1);
    int pw = (q0 & 255) * 0x01010101;
    int4 pad4; pad4.x = pw; pad4.y = pw; pad4.z = pw; pad4.w = pw;

    const signed char* qxtb = qxt + (size_t)b * L_ * 128;

    // A staging precompute: thread t owns rows (t>>3) and (t>>3)+32, 16B chunk t&7
    int chA = t & 7;
    int rowA0 = t >> 3, rowA1 = rowA0 + 32;
    int li0 = l0 + rowA0, li1 = l0 + rowA1;
    int oh0 = li0 / HW_, ow0 = li0 - oh0 * HW_;
    int oh1 = li1 / HW_, ow1 = li1 - oh1 * HW_;

    int lane = t & 63, w = t >> 6;
    int wm = (w >> 1) * 32, wn = (w & 1) * 64;
    int r = lane & 31, hi = lane >> 5;

    i32x16 acc0, acc1;
    #pragma unroll
    for (int i = 0; i < 16; ++i) { acc0[i] = 0; acc1[i] = 0; }

    for (int j = 0; j < 9; ++j) {
        int kh = j / 3, kw = j - kh * 3;
        // ---- stage A (8 KB): rows swizzled chunk ^= row&7 ----
        {
            int ih = oh0 + kh - 1, iw = ow0 + kw - 1;
            int4 v = pad4;
            if ((unsigned)ih < HW_ && (unsigned)iw < HW_)
                v = *(const int4*)(qxtb + ((ih * HW_ + iw) << 7) + (chA << 4));
            *(int4*)&As[(rowA0 << 7) + ((chA ^ (rowA0 & 7)) << 4)] = v;
            ih = oh1 + kh - 1; iw = ow1 + kw - 1;
            v = pad4;
            if ((unsigned)ih < HW_ && (unsigned)iw < HW_)
                v = *(const int4*)(qxtb + ((ih * HW_ + iw) << 7) + (chA << 4));
            *(int4*)&As[(rowA1 << 7) + ((chA ^ (rowA1 & 7)) << 4)] = v;
        }
        // ---- stage B (16 KB): qw[j] contiguous, swizzled ----
        {
            const int4* bsrc = (const int4*)(qw + j * (CO_ * C_));
            #pragma unroll
            for (int s = 0; s < 4; ++s) {
                int slot = t + s * 256;
                int o = slot >> 3, ch = slot & 7;
                int4 v = bsrc[slot];
                *(int4*)&Bs[(o << 7) + ((ch ^ (o & 7)) << 4)] = v;
            }
        }
        __syncthreads();
        // ---- 8 MFMA per wave: A row=l&31, k=16*(l>>5)+0..15 contiguous ----
        i32x4 af[4];
        #pragma unroll
        for (int kk = 0; kk < 4; ++kk) {
            int ch = kk * 2 + hi;
            af[kk] = *(const i32x4*)&As[((wm + r) << 7) + ((ch ^ (r & 7)) << 4)];
        }
        #pragma unroll
        for (int kk = 0; kk < 4; ++kk) {
            int ch = kk * 2 + hi;
            int o = wn + r;
            i32x4 bf = *(const i32x4*)&Bs[(o << 7) + ((ch ^ (o & 7)) << 4)];
            acc0 = __builtin_amdgcn_mfma_i32_32x32x32_i8(af[kk], bf, acc0, 0, 0, 0);
            o = wn + 32 + r;
            bf = *(const i32x4*)&Bs[(o << 7) + ((ch ^ (o & 7)) << 4)];
            acc1 = __builtin_amdgcn_mfma_i32_32x32x32_i8(af[kk], bf, acc1, 0, 0, 0);
        }
        __syncthreads();
    }

    // epilogue: zero-point corrections, res write, global min/max
    int o0 = wn + r, o1 = wn + 32 + r;
    int zw0 = zpw[o0], c0 = ct[o0];
    int zw1 = zpw[o1], c1 = ct[o1];
    int lmin = INT32_MAX, lmax = INT32_MIN;
    #pragma unroll
    for (int g = 0; g < 16; ++g) {
        int row = (g & 3) + ((g >> 2) << 3) + (hi << 2);
        int m = mg + wm + row;
        int s = sumqx[m];
        int v0 = acc0[g] + zw0 * s + c0;
        int v1 = acc1[g] + zw1 * s + c1;
        lmin = min(lmin, min(v0, v1));
        lmax = max(lmax, max(v0, v1));
        res[m * CO_ + o0] = v0;
        res[m * CO_ + o1] = v1;
    }
    for (int m = 32; m; m >>= 1) {
        lmin = min(lmin, __shfl_xor(lmin, m));
        lmax = max(lmax, __shfl_xor(lmax, m));
    }
    if ((t & 63) == 0) { red[t >> 6] = lmin; red[4 + (t >> 6)] = lmax; }
    __syncthreads();
    if (t == 0) {
        lmin = min(min(red[0], red[1]), min(red[2], red[3]));
        lmax = max(max(red[4], red[5]), max(red[6], red[7]));
        atomicMin(&P->rmin, lmin);
        atomicMax(&P->rmax, lmax);
    }
}

// requantize + dequantize with LDS tile transpose; out [B][Cout][L]
__global__ __launch_bounds__(256) void k_deq(const int* __restrict__ abit_p, char* ws,
                                             float* __restrict__ out) {
    __shared__ int tile[64 * 65];
    QP* P = (QP*)ws;
    const int* res = (const int*)(ws + OFF_RES);
    const float* scale_w = (const float*)(ws + OFF_SW);
    int t = threadIdx.x;
    int bid = blockIdx.x;
    int lcq = bid % 49; int tmp2 = bid / 49; int ocq = tmp2 & 1; int b = tmp2 >> 1;
    int l0 = lcq * 64, o0 = ocq * 64;

    const int* resb = res + ((size_t)(b * L_ + l0)) * CO_ + o0;
    #pragma unroll
    for (int i = 0; i < 4; ++i) {
        int lr = (t >> 4) + i * 16;
        int oc4 = (t & 15) * 4;
        int4 v = *(const int4*)(resb + lr * CO_ + oc4);
        int* d = &tile[lr * 65 + oc4];
        d[0] = v.x; d[1] = v.y; d[2] = v.z; d[3] = v.w;
    }

    int abit = read_abit(abit_p);
    float sxv, zxv; get_sx(P, abit, sxv, zxv);
    int nxq = 1 << (abit - 1);
    float nlev = (float)((1 << abit) - 1);
    float rmin = (float)P->rmin, rmax = (float)P->rmax;
    float sr = nlev / fmaxf(rmax - rmin, 1e-8f);
    float zr = rintf(sr * rmin) + (float)nxq;
    float lo = -(float)nxq, hiq = (float)(nxq - 1);

    __syncthreads();

    #pragma unroll
    for (int i = 0; i < 4; ++i) {
        int o = (t >> 4) + i * 16;
        int l4 = (t & 15) * 4;
        float swsx = scale_w[o0 + o] * sxv;
        float4 f;
        #pragma unroll
        for (int jj = 0; jj < 4; ++jj) {
            int rv = tile[(l4 + jj) * 65 + o];
            float q = fminf(fmaxf(rintf(sr * (float)rv - zr), lo), hiq);
            ((float*)&f)[jj] = ((q + zr) / sr) / swsx;
        }
        *(float4*)(out + ((size_t)(b * CO_ + o0 + o)) * L_ + l0 + l4) = f;
    }
}

// ---------------- launch ----------------

extern "C" void kernel_launch(void* const* d_in, const int* in_sizes, int n_in,
                              void* d_out, int out_size, void* d_ws, size_t ws_size,
                              hipStream_t stream) {
    const float* x      = (const float*)d_in[0];
    const float* weight = (const float*)d_in[1];
    const float* bias   = (const float*)d_in[2];
    const int*   abit   = (const int*)d_in[3];
    float* out = (float*)d_out;
    char* ws = (char*)d_ws;

    int n4 = (B_ * C_ * L_) / 4;

    k_init<<<1, 64, 0, stream>>>(ws);
    k_xminmax<<<1024, 256, 0, stream>>>((const float4*)x, n4, ws);
    k_wquant<<<128, 64, 0, stream>>>(weight, bias, abit, ws);
    k_xquant<<<784, 256, 0, stream>>>(x, abit, ws);
    k_boxsum<<<M_ / 256, 256, 0, stream>>>(abit, ws);
    k_gemm<<<M_ / 64, 256, 0, stream>>>(abit, ws);
    k_deq<<<1568, 256, 0, stream>>>(abit, ws, out);
}